// Round 2
// baseline (1325.010 us; speedup 1.0000x reference)
//
#include <hip/hip_runtime.h>
#include <hip/hip_bf16.h>

#define NN 100000
#define NE 640000
#define D 128
#define NPG 8                         // nodes per 128-thread group, held in regs
#define GITERS 4                      // node-tile iterations per block
#define NODES_PER_BLOCK (2 * NPG * GITERS)   // 64

// ---------------------------------------------------------------------------
// Kernel 1: agg[target] += w_e * x[source]   (scatter in input space)
// 32 threads per edge; each thread handles one float4 (4 features).
// ---------------------------------------------------------------------------
__global__ __launch_bounds__(256) void gcn_scatter(const float* __restrict__ x,
                                                   const float* __restrict__ ew,
                                                   const int* __restrict__ src,
                                                   const int* __restrict__ tgt,
                                                   float* __restrict__ out) {
    int tid = blockIdx.x * 256 + threadIdx.x;
    int e = tid >> 5;                 // edge index
    int t = tid & 31;                 // float4 slot within the 128-wide row
    if (e >= NE) return;
    int s = src[e];
    int g = tgt[e];
    float w = ew[e];
    float4 xv = reinterpret_cast<const float4*>(x)[s * 32 + t];
    float* dst = out + (size_t)g * D + (t << 2);
    atomicAdd(dst + 0, xv.x * w);
    atomicAdd(dst + 1, xv.y * w);
    atomicAdd(dst + 2, xv.z * w);
    atomicAdd(dst + 3, xv.w * w);
}

// ---------------------------------------------------------------------------
// Kernel 2: in-place projection  row <- row @ W^T   (W is (out,in) row-major)
// block = 256 threads = 2 groups x 128; thread f computes feature f.
// W^T staged in LDS as bf16 (32KB); rows staged in LDS fp32; each thread
// accumulates NPG nodes simultaneously so LDS row reads are broadcasts.
// ---------------------------------------------------------------------------
__global__ __launch_bounds__(256) void gcn_project(const float* __restrict__ W,
                                                   float* __restrict__ io) {
    __shared__ __hip_bfloat16 Wt[D * D];        // Wt[d*D + f] = W[f][d], 32 KB
    __shared__ float rowbuf[2][NPG][D];         // 8 KB

    const int tid = threadIdx.x;
    const int f = tid & 127;
    const int grp = tid >> 7;

    // load W coalesced, store transposed as bf16
    for (int i = tid; i < (D * D / 4); i += 256) {
        float4 v = reinterpret_cast<const float4*>(W)[i];
        int ff = (i << 2) >> 7;     // out index (row of W)
        int dd = (i << 2) & 127;    // in index
        Wt[(dd + 0) * D + ff] = __float2bfloat16(v.x);
        Wt[(dd + 1) * D + ff] = __float2bfloat16(v.y);
        Wt[(dd + 2) * D + ff] = __float2bfloat16(v.z);
        Wt[(dd + 3) * D + ff] = __float2bfloat16(v.w);
    }
    __syncthreads();

    const long base = (long)blockIdx.x * NODES_PER_BLOCK;
    for (int it = 0; it < GITERS; ++it) {
        const long nb = base + it * (2 * NPG) + grp * NPG;

        // stage NPG rows (coalesced: f consecutive across threads)
        #pragma unroll
        for (int r = 0; r < NPG; ++r) {
            long node = nb + r;
            rowbuf[grp][r][f] = (node < NN) ? io[node * D + f] : 0.0f;
        }
        __syncthreads();

        float acc[NPG];
        #pragma unroll
        for (int r = 0; r < NPG; ++r) acc[r] = 0.0f;

        for (int d = 0; d < D; d += 4) {
            float w0 = __bfloat162float(Wt[(d + 0) * D + f]);
            float w1 = __bfloat162float(Wt[(d + 1) * D + f]);
            float w2 = __bfloat162float(Wt[(d + 2) * D + f]);
            float w3 = __bfloat162float(Wt[(d + 3) * D + f]);
            #pragma unroll
            for (int r = 0; r < NPG; ++r) {
                const float4 rv = *reinterpret_cast<const float4*>(&rowbuf[grp][r][d]);
                acc[r] = fmaf(rv.x, w0, acc[r]);
                acc[r] = fmaf(rv.y, w1, acc[r]);
                acc[r] = fmaf(rv.z, w2, acc[r]);
                acc[r] = fmaf(rv.w, w3, acc[r]);
            }
        }
        __syncthreads();   // all rowbuf reads done before next stage overwrites

        #pragma unroll
        for (int r = 0; r < NPG; ++r) {
            long node = nb + r;
            if (node < NN) io[node * D + f] = acc[r];
        }
    }
}

extern "C" void kernel_launch(void* const* d_in, const int* in_sizes, int n_in,
                              void* d_out, int out_size, void* d_ws, size_t ws_size,
                              hipStream_t stream) {
    const float* x   = (const float*)d_in[0];
    const float* W   = (const float*)d_in[1];
    const float* ew  = (const float*)d_in[2];
    const int*   src = (const int*)d_in[3];
    const int*   tgt = (const int*)d_in[4];
    float* out = (float*)d_out;

    hipMemsetAsync(out, 0, (size_t)out_size * sizeof(float), stream);

    int sblocks = (NE * 32 + 255) / 256;   // 80000
    gcn_scatter<<<sblocks, 256, 0, stream>>>(x, ew, src, tgt, out);

    int pblocks = (NN + NODES_PER_BLOCK - 1) / NODES_PER_BLOCK;  // 1563
    gcn_project<<<pblocks, 256, 0, stream>>>(W, out);
}

// Round 5
// 314.258 us; speedup vs baseline: 4.2163x; 4.2163x over previous
//
#include <hip/hip_runtime.h>
#include <hip/hip_bf16.h>

#define NN 100000
#define NE 640000
#define D 128

#define SCAN_CHUNK 1024
#define NBLK ((NN + SCAN_CHUNK - 1) / SCAN_CHUNK)   // 98

// ---- workspace layout (bytes) ----
#define OFF_COUNTS  0u
#define OFF_OFFSETS 400000u                    // NN*4
#define OFF_CURSOR  800016u                    // OFF_OFFSETS + (NN+1)*4, padded
#define OFF_BSUM    1200016u
#define OFF_BSUMEX  1200528u
#define OFF_PSRC    1201040u
#define OFF_PW      3761040u                   // OFF_PSRC + NE*4
#define WS_NEED     6321040u                   // OFF_PW + NE*4

// ---------------------------------------------------------------------------
// CSR build: histogram of targets
// ---------------------------------------------------------------------------
__global__ __launch_bounds__(256) void k_hist(const int* __restrict__ tgt,
                                              int* __restrict__ counts) {
    int e = blockIdx.x * 256 + threadIdx.x;
    if (e < NE) atomicAdd(&counts[tgt[e]], 1);
}

// block-level partial sums of counts (1024 per block)
__global__ __launch_bounds__(256) void k_scan_part(const int* __restrict__ counts,
                                                   int* __restrict__ bsum) {
    __shared__ int sd[256];
    int b = blockIdx.x, t = threadIdx.x;
    int base = b * SCAN_CHUNK + t * 4;
    int s = 0;
    #pragma unroll
    for (int k = 0; k < 4; ++k) { int i = base + k; s += (i < NN) ? counts[i] : 0; }
    sd[t] = s; __syncthreads();
    for (int off = 128; off > 0; off >>= 1) {
        if (t < off) sd[t] += sd[t + off];
        __syncthreads();
    }
    if (t == 0) bsum[b] = sd[0];
}

// exclusive scan of the (<=128) block sums; also writes offsets[NN]=NE
__global__ __launch_bounds__(128) void k_scan_mid(const int* __restrict__ bsum,
                                                  int* __restrict__ bsumex,
                                                  int* __restrict__ offsets) {
    __shared__ int sd[128];
    int t = threadIdx.x;
    int v = (t < NBLK) ? bsum[t] : 0;
    sd[t] = v; __syncthreads();
    for (int off = 1; off < 128; off <<= 1) {
        int tmp = (t >= off) ? sd[t - off] : 0;
        __syncthreads();
        sd[t] += tmp;
        __syncthreads();
    }
    if (t < NBLK) bsumex[t] = sd[t] - v;
    if (t == 0) offsets[NN] = NE;
}

// per-block exclusive scan + block offset -> offsets & cursor
__global__ __launch_bounds__(256) void k_scan_final(const int* __restrict__ counts,
                                                    const int* __restrict__ bsumex,
                                                    int* __restrict__ offsets,
                                                    int* __restrict__ cursor) {
    __shared__ int sd[256];
    int b = blockIdx.x, t = threadIdx.x;
    int base = b * SCAN_CHUNK + t * 4;
    int c[4]; int s = 0;
    #pragma unroll
    for (int k = 0; k < 4; ++k) { int i = base + k; c[k] = (i < NN) ? counts[i] : 0; s += c[k]; }
    sd[t] = s; __syncthreads();
    for (int off = 1; off < 256; off <<= 1) {
        int tmp = (t >= off) ? sd[t - off] : 0;
        __syncthreads();
        sd[t] += tmp;
        __syncthreads();
    }
    int run = sd[t] - s + bsumex[b];   // exclusive prefix + block base
    #pragma unroll
    for (int k = 0; k < 4; ++k) {
        int i = base + k;
        if (i < NN) { offsets[i] = run; cursor[i] = run; }
        run += c[k];
    }
}

// bucket edges by target (1 int atomic per edge)
__global__ __launch_bounds__(256) void k_fill(const int* __restrict__ src,
                                              const int* __restrict__ tgt,
                                              const float* __restrict__ ew,
                                              int* __restrict__ cursor,
                                              int* __restrict__ psrc,
                                              float* __restrict__ pw) {
    int e = blockIdx.x * 256 + threadIdx.x;
    if (e < NE) {
        int t = tgt[e];
        int p = atomicAdd(&cursor[t], 1);
        psrc[p] = src[e];
        pw[p] = ew[e];
    }
}

// ---------------------------------------------------------------------------
// Pull-mode aggregation: one wave (64 lanes) per target node, zero atomics.
// out[n] = sum_{e in CSR[n]} pw[e] * x[psrc[e]]   (writes every row once)
// ---------------------------------------------------------------------------
__global__ __launch_bounds__(256) void k_gather(const float* __restrict__ x,
                                                const int* __restrict__ offsets,
                                                const int* __restrict__ psrc,
                                                const float* __restrict__ pw,
                                                float* __restrict__ out) {
    int wid = blockIdx.x * 4 + (threadIdx.x >> 6);
    int lane = threadIdx.x & 63;
    if (wid >= NN) return;
    int beg = offsets[wid], end = offsets[wid + 1];
    const float2* x2 = (const float2*)x;
    float a0 = 0.f, a1 = 0.f;
    int s = 0; float w = 0.f;
    if (beg < end) { s = psrc[beg]; w = pw[beg]; }
    for (int i = beg; i < end; ++i) {
        int sn = 0; float wn = 0.f;
        if (i + 1 < end) { sn = psrc[i + 1]; wn = pw[i + 1]; }  // prefetch next idx
        float2 v = x2[(size_t)s * 64 + lane];
        a0 = fmaf(v.x, w, a0);
        a1 = fmaf(v.y, w, a1);
        s = sn; w = wn;
    }
    ((float2*)out)[(size_t)wid * 64 + lane] = make_float2(a0, a1);
}

// ---------------------------------------------------------------------------
// In-place projection: io[n] <- io[n] @ W^T, register-tiled 4 nodes x 8 feats
// per thread. W staged in LDS as bf16 Wb[d][f]; 64 node-rows staged fp32.
// ---------------------------------------------------------------------------
#define PBN 64   // nodes per block

__device__ __forceinline__ float bflo(unsigned u) { return __uint_as_float(u << 16); }
__device__ __forceinline__ float bfhi(unsigned u) { return __uint_as_float(u & 0xffff0000u); }

__global__ __launch_bounds__(256) void k_project(const float* __restrict__ W,
                                                 float* __restrict__ io) {
    __shared__ __align__(16) float xs[PBN][D];            // 32 KB
    __shared__ __align__(16) __hip_bfloat16 Wb[D][D];     // 32 KB, Wb[d][f] = W[f][d]

    const int tid = threadIdx.x;

    // stage W transposed: lane-consecutive f -> conflict-free LDS writes.
    // global reads are 16B-strided but W is tiny and L2-hot.
    const float4* W4 = (const float4*)W;
    for (int k = 0; k < 16; ++k) {
        int idx = k * 256 + tid;          // 0..4095
        int f = idx & 127;
        int dq = idx >> 7;                // 0..31
        float4 v = W4[(size_t)f * 32 + dq];
        Wb[dq * 4 + 0][f] = __float2bfloat16(v.x);
        Wb[dq * 4 + 1][f] = __float2bfloat16(v.y);
        Wb[dq * 4 + 2][f] = __float2bfloat16(v.z);
        Wb[dq * 4 + 3][f] = __float2bfloat16(v.w);
    }

    // stage 64 node rows (coalesced float4)
    const long nb = (long)blockIdx.x * PBN;
    const float4* io4 = (const float4*)io;
    for (int k = 0; k < 8; ++k) {
        int idx = k * 256 + tid;          // 0..2047
        int n = idx >> 5;
        int dq = idx & 31;
        long node = nb + n;
        float4 v = (node < NN) ? io4[node * 32 + dq] : make_float4(0.f, 0.f, 0.f, 0.f);
        *(float4*)&xs[n][dq * 4] = v;
    }
    __syncthreads();

    const int fg = tid & 15;   // features fg*8 .. fg*8+7
    const int ng = tid >> 4;   // nodes ng*4 .. ng*4+3
    float acc[4][8];
    #pragma unroll
    for (int r = 0; r < 4; ++r)
        #pragma unroll
        for (int ff = 0; ff < 8; ++ff) acc[r][ff] = 0.f;

    for (int d = 0; d < D; d += 4) {
        float4 xv[4];
        #pragma unroll
        for (int r = 0; r < 4; ++r) xv[r] = *(const float4*)&xs[ng * 4 + r][d];
        #pragma unroll
        for (int j = 0; j < 4; ++j) {
            uint4 wv = *(const uint4*)&Wb[d + j][fg * 8];
            float wf0 = bflo(wv.x), wf1 = bfhi(wv.x);
            float wf2 = bflo(wv.y), wf3 = bfhi(wv.y);
            float wf4 = bflo(wv.z), wf5 = bfhi(wv.z);
            float wf6 = bflo(wv.w), wf7 = bfhi(wv.w);
            #pragma unroll
            for (int r = 0; r < 4; ++r) {
                float xj = ((const float*)&xv[r])[j];
                acc[r][0] = fmaf(xj, wf0, acc[r][0]);
                acc[r][1] = fmaf(xj, wf1, acc[r][1]);
                acc[r][2] = fmaf(xj, wf2, acc[r][2]);
                acc[r][3] = fmaf(xj, wf3, acc[r][3]);
                acc[r][4] = fmaf(xj, wf4, acc[r][4]);
                acc[r][5] = fmaf(xj, wf5, acc[r][5]);
                acc[r][6] = fmaf(xj, wf6, acc[r][6]);
                acc[r][7] = fmaf(xj, wf7, acc[r][7]);
            }
        }
    }

    #pragma unroll
    for (int r = 0; r < 4; ++r) {
        long node = nb + ng * 4 + r;
        if (node < NN) {
            float4* dst = (float4*)&io[node * D + fg * 8];
            dst[0] = make_float4(acc[r][0], acc[r][1], acc[r][2], acc[r][3]);
            dst[1] = make_float4(acc[r][4], acc[r][5], acc[r][6], acc[r][7]);
        }
    }
}

// ---------------------------------------------------------------------------
// Fallback (ws too small): direct atomic scatter in x-space
// ---------------------------------------------------------------------------
__global__ __launch_bounds__(256) void gcn_scatter(const float* __restrict__ x,
                                                   const float* __restrict__ ew,
                                                   const int* __restrict__ src,
                                                   const int* __restrict__ tgt,
                                                   float* __restrict__ out) {
    int tid = blockIdx.x * 256 + threadIdx.x;
    int e = tid >> 5;
    int t = tid & 31;
    if (e >= NE) return;
    int s = src[e];
    int g = tgt[e];
    float w = ew[e];
    float4 xv = reinterpret_cast<const float4*>(x)[s * 32 + t];
    float* dst = out + (size_t)g * D + (t << 2);
    atomicAdd(dst + 0, xv.x * w);
    atomicAdd(dst + 1, xv.y * w);
    atomicAdd(dst + 2, xv.z * w);
    atomicAdd(dst + 3, xv.w * w);
}

extern "C" void kernel_launch(void* const* d_in, const int* in_sizes, int n_in,
                              void* d_out, int out_size, void* d_ws, size_t ws_size,
                              hipStream_t stream) {
    const float* x   = (const float*)d_in[0];
    const float* W   = (const float*)d_in[1];
    const float* ew  = (const float*)d_in[2];
    const int*   src = (const int*)d_in[3];
    const int*   tgt = (const int*)d_in[4];
    float* out = (float*)d_out;

    if (ws_size >= WS_NEED) {
        char* ws = (char*)d_ws;
        int*   counts  = (int*)(ws + OFF_COUNTS);
        int*   offsets = (int*)(ws + OFF_OFFSETS);
        int*   cursor  = (int*)(ws + OFF_CURSOR);
        int*   bsum    = (int*)(ws + OFF_BSUM);
        int*   bsumex  = (int*)(ws + OFF_BSUMEX);
        int*   psrc    = (int*)(ws + OFF_PSRC);
        float* pw      = (float*)(ws + OFF_PW);

        hipMemsetAsync(counts, 0, (size_t)NN * sizeof(int), stream);
        k_hist<<<(NE + 255) / 256, 256, 0, stream>>>(tgt, counts);
        k_scan_part<<<NBLK, 256, 0, stream>>>(counts, bsum);
        k_scan_mid<<<1, 128, 0, stream>>>(bsum, bsumex, offsets);
        k_scan_final<<<NBLK, 256, 0, stream>>>(counts, bsumex, offsets, cursor);
        k_fill<<<(NE + 255) / 256, 256, 0, stream>>>(src, tgt, ew, cursor, psrc, pw);
        k_gather<<<(NN + 3) / 4, 256, 0, stream>>>(x, offsets, psrc, pw, out);
    } else {
        hipMemsetAsync(out, 0, (size_t)out_size * sizeof(float), stream);
        gcn_scatter<<<(NE * 32 + 255) / 256, 256, 0, stream>>>(x, ew, src, tgt, out);
    }

    k_project<<<(NN + PBN - 1) / PBN, 256, 0, stream>>>(W, out);
}